// Round 1
// baseline (25252.753 us; speedup 1.0000x reference)
//
#include <hip/hip_runtime.h>
#include <hip/hip_bf16.h>

namespace {
constexpr int B  = 64;
constexpr int T  = 2048;
constexpr int L  = 200;
constexpr int H  = 256;
constexpr int KV = 256;
constexpr int E  = 256;
constexpr int V  = 33;
constexpr int MH = 512;
constexpr int G  = 4 * H;        // 1024 gate rows per cell
constexpr int HB = H * B;        // 16384

// float workspace layout (offsets in floats)
constexpr long OFF_H   = 0;                        // h double buffer [2][3][H][B]
constexpr long OFF_C   = OFF_H  + 2L * 3 * HB;     // c [3][H][B]
constexpr long OFF_CTX = OFF_C  + 3L * HB;         // ctx' double buffer [2][KV][B]
constexpr long OFF_Z   = OFF_CTX + 2L * KV * B;    // Z' [2][B]
constexpr long OFF_M   = OFF_Z  + 2L * B;          // m [B]
constexpr long OFF_E   = OFF_M  + B;               // e [B][T]
constexpr long OFF_HID = OFF_E  + (long)B * T;     // hiddenT [MH][B]
constexpr long OFF_XE  = OFF_HID + (long)MH * B;   // xembT [L][E][B]
constexpr long FLOATS  = OFF_XE + (long)L * E * B;
constexpr long FLOATBYTES = FLOATS * 4;            // 14,484,224 B (16B aligned)
constexpr long KVELEMS = (long)B * T * KV;         // 33,554,432
constexpr long NEED_BF = FLOATBYTES + 2 * KVELEMS * 2; // ~148.7 MB
}

__device__ __forceinline__ float sigm(float x) { return 1.f / (1.f + __expf(-x)); }
__device__ __forceinline__ float tanh_f(float x) {
  float xc = fminf(fmaxf(x, -15.f), 15.f);
  float e2 = __expf(2.f * xc);
  return (e2 - 1.f) / (e2 + 1.f);
}
__device__ __forceinline__ ushort f2bf(float x) {
  unsigned u = __float_as_uint(x);
  unsigned r = (u + 0x7fffu + ((u >> 16) & 1u)) >> 16;
  return (ushort)r;
}
__device__ __forceinline__ float bf2f(unsigned v) { return __uint_as_float(v << 16); }

__device__ __forceinline__ void atomicMaxFloat(float* p, float v) {
  int old = __float_as_int(*p);
  while (__int_as_float(old) < v) {
    int assumed = old;
    old = atomicCAS((int*)p, assumed, __float_as_int(v));
    if (old == assumed) break;
  }
}

// ---------- one-time kernels ----------
__global__ void k_init(float* __restrict__ ws) {
  int i = blockIdx.x * blockDim.x + threadIdx.x;
  if (i < 3 * HB) { ws[OFF_H + i] = 0.f; ws[OFF_C + i] = 0.f; }  // h buf0, c
  if (i < KV * B) ws[OFF_CTX + i] = 0.f;                          // ctx buf0
  if (i < B)      ws[OFF_Z + i] = 1.f;                            // Z buf0 = 1
}

__global__ void k_embed(const int* __restrict__ labels, const float* __restrict__ emb,
                        float* __restrict__ xembT) {
  int i = blockIdx.x * blockDim.x + threadIdx.x;
  if (i >= L * E * B) return;
  int b = i & 63, e = (i >> 6) & 255, l = i >> 14;
  int lab = labels[l * B + b];
  xembT[i] = emb[lab * E + e];
}

__global__ void k_cvt(const float4* __restrict__ src, ushort4* __restrict__ dst, int n4) {
  int i = blockIdx.x * blockDim.x + threadIdx.x;
  int stride = gridDim.x * blockDim.x;
  for (int k = i; k < n4; k += stride) {
    float4 v = src[k];
    ushort4 o;
    o.x = f2bf(v.x); o.y = f2bf(v.y); o.z = f2bf(v.z); o.w = f2bf(v.w);
    dst[k] = o;
  }
}

// ---------- LSTM cells ----------
// block 512 = 64 b-lanes x 4 gates x 2 k-splits; grid = H (one j per block)
__global__ __launch_bounds__(512) void k_cell0(
    const float* __restrict__ wih, const float* __restrict__ whh,
    const float* __restrict__ bih, const float* __restrict__ bhh,
    const float* __restrict__ xe,          // [E][B] for this step
    const float* __restrict__ ctx, const float* __restrict__ Z,
    const float* __restrict__ hprev,       // layer0 prev [H][B]
    float* __restrict__ hnew, float* __restrict__ cst) {
  int t = threadIdx.x;
  int b = t & 63, q = (t >> 6) & 3, ks = t >> 8;
  int j = blockIdx.x;
  int row = q * H + j;
  float acc = 0.f, s0 = 0.f, s1 = 0.f, s2 = 0.f, s3 = 0.f, a2 = 0.f;
  if (ks == 0) {
    acc = bih[row] + bhh[row];
    const float* wi = wih + (long)row * (E + KV);
    #pragma unroll 4
    for (int k = 0; k < E; k += 4) {
      s0 += wi[k]   * xe[(k)   * B + b];
      s1 += wi[k+1] * xe[(k+1) * B + b];
      s2 += wi[k+2] * xe[(k+2) * B + b];
      s3 += wi[k+3] * xe[(k+3) * B + b];
    }
    const float* wh = whh + (long)row * H;
    #pragma unroll 4
    for (int k = 0; k < 128; k += 2) {
      a2 += wh[k]   * hprev[(k)   * B + b];
      a2 += wh[k+1] * hprev[(k+1) * B + b];
    }
    acc += (s0 + s1) + (s2 + s3) + a2;
  } else {
    float zz = 1.f / fmaxf(Z[b], 1e-12f);
    const float* wi = wih + (long)row * (E + KV) + E;
    #pragma unroll 4
    for (int k = 0; k < KV; k += 4) {
      s0 += wi[k]   * ctx[(k)   * B + b];
      s1 += wi[k+1] * ctx[(k+1) * B + b];
      s2 += wi[k+2] * ctx[(k+2) * B + b];
      s3 += wi[k+3] * ctx[(k+3) * B + b];
    }
    const float* wh = whh + (long)row * H + 128;
    #pragma unroll 4
    for (int k = 0; k < 128; k += 2) {
      a2 += wh[k]   * hprev[(128 + k)     * B + b];
      a2 += wh[k+1] * hprev[(128 + k + 1) * B + b];
    }
    acc = ((s0 + s1) + (s2 + s3)) * zz + a2;
  }
  __shared__ float sh[2][4][64];
  sh[ks][q][b] = acc;
  __syncthreads();
  if (t < 64) {
    int bb = t;
    float gi = sh[0][0][bb] + sh[1][0][bb];
    float gf = sh[0][1][bb] + sh[1][1][bb];
    float gg = sh[0][2][bb] + sh[1][2][bb];
    float go = sh[0][3][bb] + sh[1][3][bb];
    float c = sigm(gf) * cst[j * B + bb] + sigm(gi) * tanh_f(gg);
    float h = sigm(go) * tanh_f(c);
    cst[j * B + bb] = c;
    hnew[j * B + bb] = h;
  }
}

// layers 1,2: input = hin [H][B], recurrent = hprevL
__global__ __launch_bounds__(512) void k_cellr(
    const float* __restrict__ wih, const float* __restrict__ whh,
    const float* __restrict__ bih, const float* __restrict__ bhh,
    const float* __restrict__ hin, const float* __restrict__ hprevL,
    float* __restrict__ hnewL, float* __restrict__ cst,
    float* __restrict__ ctxn, float* __restrict__ Zn, float* __restrict__ m, int aux) {
  int t = threadIdx.x;
  int b = t & 63, q = (t >> 6) & 3, ks = t >> 8;
  int j = blockIdx.x;
  int row = q * H + j;
  if (aux) {  // prepare next-step attention accumulators
    int gid = blockIdx.x * 512 + t;
    if (gid < KV * B) ctxn[gid] = 0.f;
    if (gid < B) { Zn[gid] = 0.f; m[gid] = -3.4e38f; }
  }
  float acc = ks ? 0.f : (bih[row] + bhh[row]);
  float a1 = 0.f, a2 = 0.f, a3 = 0.f, a4 = 0.f;
  const float* wi = wih + (long)row * H + ks * 128;
  const float* wh = whh + (long)row * H + ks * 128;
  int k0 = ks * 128;
  #pragma unroll 4
  for (int k = 0; k < 128; k += 2) {
    a1 += wi[k]   * hin[(k0 + k)     * B + b];
    a2 += wi[k+1] * hin[(k0 + k + 1) * B + b];
    a3 += wh[k]   * hprevL[(k0 + k)     * B + b];
    a4 += wh[k+1] * hprevL[(k0 + k + 1) * B + b];
  }
  acc += (a1 + a2) + (a3 + a4);
  __shared__ float sh[2][4][64];
  sh[ks][q][b] = acc;
  __syncthreads();
  if (t < 64) {
    int bb = t;
    float gi = sh[0][0][bb] + sh[1][0][bb];
    float gf = sh[0][1][bb] + sh[1][1][bb];
    float gg = sh[0][2][bb] + sh[1][2][bb];
    float go = sh[0][3][bb] + sh[1][3][bb];
    float c = sigm(gf) * cst[j * B + bb] + sigm(gi) * tanh_f(gg);
    float h = sigm(go) * tanh_f(c);
    cst[j * B + bb] = c;
    hnewL[j * B + bb] = h;
  }
}

// ---------- attention ----------
// wave-per-row: lane d holds 4 features; grid (T/64, B), block 256 (4 waves x 16 rows)
template <int BF>
__global__ __launch_bounds__(256) void k_energy(
    const void* __restrict__ keyp, const float* __restrict__ h2,
    const int* __restrict__ lens, float* __restrict__ e, float* __restrict__ m) {
  int b = blockIdx.y;
  int len = lens[b];
  int wave = threadIdx.x >> 6, lane = threadIdx.x & 63;
  int t0 = (blockIdx.x * 4 + wave) * 16;
  if (t0 >= len) return;
  float h0 = h2[(4 * lane + 0) * B + b];
  float h1 = h2[(4 * lane + 1) * B + b];
  float h2v = h2[(4 * lane + 2) * B + b];
  float h3 = h2[(4 * lane + 3) * B + b];
  int tend = min(t0 + 16, len);
  float wmax = -3.4e38f;
  for (int t = t0; t < tend; t++) {
    float4 kv;
    if (BF) {
      const uint2* p = (const uint2*)((const ushort*)keyp + (size_t)(b * T + t) * KV + 4 * lane);
      uint2 d = *p;
      kv.x = bf2f(d.x & 0xffffu);
      kv.y = __uint_as_float(d.x & 0xffff0000u);
      kv.z = bf2f(d.y & 0xffffu);
      kv.w = __uint_as_float(d.y & 0xffff0000u);
    } else {
      kv = ((const float4*)((const float*)keyp + (size_t)(b * T + t) * KV))[lane];
    }
    float s = kv.x * h0 + kv.y * h1 + kv.z * h2v + kv.w * h3;
    #pragma unroll
    for (int off = 32; off; off >>= 1) s += __shfl_xor(s, off, 64);
    if (lane == 0) e[b * T + t] = s;
    wmax = fmaxf(wmax, s);
  }
  if (lane == 0) atomicMaxFloat(&m[b], wmax);
}

// exp(e-m) * V accumulate; grid (T/256, B), block 256 (4 waves x 64 rows)
template <int BF>
__global__ __launch_bounds__(256) void k_pv(
    const void* __restrict__ valp, const float* __restrict__ e, const float* __restrict__ m,
    const int* __restrict__ lens, float* __restrict__ ctxn, float* __restrict__ Zn) {
  int b = blockIdx.y;
  int len = lens[b];
  int t0blk = blockIdx.x * 256;
  if (t0blk >= len) return;
  int wave = threadIdx.x >> 6, lane = threadIdx.x & 63;
  float mb = m[b];
  float a0 = 0.f, a1 = 0.f, a2 = 0.f, a3 = 0.f, zp = 0.f;
  int t0 = t0blk + wave * 64;
  int tend = min(t0 + 64, len);
  for (int t = t0; t < tend; t++) {
    float w = __expf(e[b * T + t] - mb);
    float4 vv;
    if (BF) {
      const uint2* p = (const uint2*)((const ushort*)valp + (size_t)(b * T + t) * KV + 4 * lane);
      uint2 d = *p;
      vv.x = bf2f(d.x & 0xffffu);
      vv.y = __uint_as_float(d.x & 0xffff0000u);
      vv.z = bf2f(d.y & 0xffffu);
      vv.w = __uint_as_float(d.y & 0xffff0000u);
    } else {
      vv = ((const float4*)((const float*)valp + (size_t)(b * T + t) * KV))[lane];
    }
    a0 += w * vv.x; a1 += w * vv.y; a2 += w * vv.z; a3 += w * vv.w;
    zp += w;
  }
  __shared__ float sh[4][256];
  __shared__ float shz[4];
  sh[wave][4 * lane + 0] = a0;
  sh[wave][4 * lane + 1] = a1;
  sh[wave][4 * lane + 2] = a2;
  sh[wave][4 * lane + 3] = a3;
  if (lane == 0) shz[wave] = zp;
  __syncthreads();
  if (wave == 0) {
    #pragma unroll
    for (int r = 0; r < 4; r++) {
      int d = lane * 4 + r;
      float s = sh[0][d] + sh[1][d] + sh[2][d] + sh[3][d];
      atomicAdd(&ctxn[d * B + b], s);
    }
    if (lane == 0) atomicAdd(&Zn[b], shz[0] + shz[1] + shz[2] + shz[3]);
  }
}

// ---------- MLP head ----------
__global__ __launch_bounds__(256) void k_fc1(
    const float* __restrict__ w, const float* __restrict__ bias,
    const float* __restrict__ h2, const float* __restrict__ ctxn, const float* __restrict__ Zn,
    float* __restrict__ hid) {
  int t = threadIdx.x;
  int b = t & 63, jl = t >> 6;
  int j = blockIdx.x * 4 + jl;
  float zz = 1.f / fmaxf(Zn[b], 1e-12f);
  const float* wr = w + (long)j * (H + KV);
  float s0 = 0.f, s1 = 0.f, s2 = 0.f, s3 = 0.f, a2 = 0.f, a3 = 0.f;
  #pragma unroll 4
  for (int k = 0; k < H; k += 4) {
    s0 += wr[k]   * h2[(k)   * B + b];
    s1 += wr[k+1] * h2[(k+1) * B + b];
    s2 += wr[k+2] * h2[(k+2) * B + b];
    s3 += wr[k+3] * h2[(k+3) * B + b];
  }
  #pragma unroll 4
  for (int k = 0; k < KV; k += 2) {
    a2 += wr[H + k]     * ctxn[(k)   * B + b];
    a3 += wr[H + k + 1] * ctxn[(k+1) * B + b];
  }
  float acc = bias[j] + (s0 + s1) + (s2 + s3) + (a2 + a3) * zz;
  hid[j * B + b] = fmaxf(acc, 0.f);
}

__global__ __launch_bounds__(64) void k_fc2(
    const float* __restrict__ w, const float* __restrict__ bias,
    const float* __restrict__ hid, float* __restrict__ out, int step) {
  int b = threadIdx.x;
  int v = blockIdx.x;
  const float* wr = w + (long)v * MH;
  float s0 = 0.f, s1 = 0.f, s2 = 0.f, s3 = 0.f;
  #pragma unroll 4
  for (int k = 0; k < MH; k += 4) {
    s0 += wr[k]   * hid[(k)   * B + b];
    s1 += wr[k+1] * hid[(k+1) * B + b];
    s2 += wr[k+2] * hid[(k+2) * B + b];
    s3 += wr[k+3] * hid[(k+3) * B + b];
  }
  out[((long)b * L + step) * V + v] = bias[v] + (s0 + s1) + (s2 + s3);
}

extern "C" void kernel_launch(void* const* d_in, const int* in_sizes, int n_in,
                              void* d_out, int out_size, void* d_ws, size_t ws_size,
                              hipStream_t stream) {
  const float* key    = (const float*)d_in[0];
  const float* value  = (const float*)d_in[1];
  const int*   labels = (const int*)d_in[2];
  const int*   lens   = (const int*)d_in[3];
  const float* emb    = (const float*)d_in[4];
  const float* w_ih0  = (const float*)d_in[5];
  const float* w_hh0  = (const float*)d_in[6];
  const float* b_ih0  = (const float*)d_in[7];
  const float* b_hh0  = (const float*)d_in[8];
  const float* w_ihr  = (const float*)d_in[9];
  const float* w_hhr  = (const float*)d_in[10];
  const float* b_ihr  = (const float*)d_in[11];
  const float* b_hhr  = (const float*)d_in[12];
  const float* fc1_w  = (const float*)d_in[13];
  const float* fc1_b  = (const float*)d_in[14];
  const float* fc2_w  = (const float*)d_in[15];
  const float* fc2_b  = (const float*)d_in[16];
  float* out = (float*)d_out;
  float* ws  = (float*)d_ws;

  float* hbuf = ws + OFF_H;
  float* cbuf = ws + OFF_C;
  float* ctxb = ws + OFF_CTX;
  float* Zb   = ws + OFF_Z;
  float* mb   = ws + OFF_M;
  float* eb   = ws + OFF_E;
  float* hid  = ws + OFF_HID;
  float* xe   = ws + OFF_XE;

  bool bf = ((long)ws_size >= NEED_BF);
  ushort* kbf = (ushort*)((char*)d_ws + FLOATBYTES);
  ushort* vbf = kbf + KVELEMS;

  k_init<<<(3 * HB + 255) / 256, 256, 0, stream>>>(ws);
  k_embed<<<(L * E * B + 255) / 256, 256, 0, stream>>>(labels, emb, xe);
  if (bf) {
    int n4 = (int)(KVELEMS >> 2);
    k_cvt<<<4096, 256, 0, stream>>>((const float4*)key, (ushort4*)kbf, n4);
    k_cvt<<<4096, 256, 0, stream>>>((const float4*)value, (ushort4*)vbf, n4);
  }

  for (int t = 0; t < L; t++) {
    int cur = t & 1, nxt = cur ^ 1;
    float* hprev = hbuf + (long)cur * 3 * HB;
    float* hnew  = hbuf + (long)nxt * 3 * HB;
    float* ctxc  = ctxb + (long)cur * KV * B;
    float* ctxn  = ctxb + (long)nxt * KV * B;
    float* Zc = Zb + cur * B;
    float* Zn = Zb + nxt * B;

    k_cell0<<<H, 512, 0, stream>>>(w_ih0, w_hh0, b_ih0, b_hh0,
                                   xe + (long)t * E * B, ctxc, Zc,
                                   hprev, hnew, cbuf);
    k_cellr<<<H, 512, 0, stream>>>(w_ihr, w_hhr, b_ihr, b_hhr,
                                   hnew, hprev + HB, hnew + HB, cbuf + HB,
                                   ctxn, Zn, mb, 1);
    k_cellr<<<H, 512, 0, stream>>>(w_ihr + (long)G * H, w_hhr + (long)G * H,
                                   b_ihr + G, b_hhr + G,
                                   hnew + HB, hprev + 2 * HB, hnew + 2 * HB, cbuf + 2 * HB,
                                   nullptr, nullptr, nullptr, 0);
    if (bf) {
      k_energy<1><<<dim3(T / 64, B), 256, 0, stream>>>(kbf, hnew + 2 * HB, lens, eb, mb);
      k_pv<1><<<dim3(T / 256, B), 256, 0, stream>>>(vbf, eb, mb, lens, ctxn, Zn);
    } else {
      k_energy<0><<<dim3(T / 64, B), 256, 0, stream>>>(key, hnew + 2 * HB, lens, eb, mb);
      k_pv<0><<<dim3(T / 256, B), 256, 0, stream>>>(value, eb, mb, lens, ctxn, Zn);
    }
    k_fc1<<<MH / 4, 256, 0, stream>>>(fc1_w, fc1_b, hnew + 2 * HB, ctxn, Zn, hid);
    k_fc2<<<V, 64, 0, stream>>>(fc2_w, fc2_b, hid, out, t);
  }
}